// Round 13
// baseline (750.859 us; speedup 1.0000x reference)
//
#include <hip/hip_runtime.h>

typedef __attribute__((ext_vector_type(8))) short short8;
typedef __attribute__((ext_vector_type(4))) float float4v;
typedef __attribute__((ext_vector_type(4))) int int4v;
typedef __attribute__((ext_vector_type(4))) unsigned short ushort4v;

#define NBOX 13392   // 108*124 bev cells (n = d*124 + wj)
#define ZC 9
#define KOFT 2304    // 9*256, k = z*256+c
#define NPIX 3348    // 62*54
#define NBLK0 105    // ceil(13392/128)
#define NBLKC 27     // ceil(3348/128)
#define TILEK 4096   // shorts per 8KB step-tile
#define NBSTRIDE 294912  // 72 steps * 4096 shorts per row-block / col-block
#define VOXSZ 30965760   // NBLK0*NBSTRIDE shorts per scale
#define TAPINTS 16       // compressed tap record: 16 ints = 64 B per box

__device__ __forceinline__ unsigned short f2bf(float f) {
  union { float f; unsigned int i; } v; v.f = f;
  unsigned int r = v.i + 0x7FFFu + ((v.i >> 16) & 1u);
  return (unsigned short)(r >> 16);
}
__device__ __forceinline__ float bf2f(unsigned short u) {
  union { unsigned int i; float f; } v; v.i = ((unsigned int)u) << 16; return v.f;
}
__device__ __forceinline__ float i2f(int i) {
  union { int i; float f; } v; v.i = i; return v.f;
}

__device__ __constant__ int cHFs[5] = {96, 48, 24, 12, 6};
__device__ __constant__ int cWFs[5] = {320, 160, 80, 40, 20};
__device__ __constant__ size_t cIIof[5] = {0, 7864320, 9830400, 10321920, 10444800};

// wave-uniform pointer: readfirstlane both halves so loads become s_load
__device__ __forceinline__ const int* uniform_ptr(const int* p) {
  unsigned lo = (unsigned)(uintptr_t)p;
  unsigned hi = (unsigned)((uintptr_t)p >> 32);
  lo = (unsigned)__builtin_amdgcn_readfirstlane((int)lo);
  hi = (unsigned)__builtin_amdgcn_readfirstlane((int)hi);
  return (const int*)(((uintptr_t)hi << 32) | (uintptr_t)lo);
}

// async 16B global->LDS (wave-uniform LDS base + lane*16)
__device__ __forceinline__ void async16(const unsigned short* g, unsigned short* l) {
  __builtin_amdgcn_global_load_lds(
      (const __attribute__((address_space(1))) unsigned int*)g,
      (__attribute__((address_space(3))) unsigned int*)l, 16, 0, 0);
}

// ---------------- alpha/beta epilogue constants + zero MEANS + zero page ---
__global__ void k_alpha_beta(const float* __restrict__ oft_b,
                             const float* __restrict__ g1, const float* __restrict__ b1,
                             const float* __restrict__ m1, const float* __restrict__ v1,
                             const float* __restrict__ g2, const float* __restrict__ b2,
                             const float* __restrict__ m2, const float* __restrict__ v2,
                             float* __restrict__ ALPHA, float* __restrict__ BETA,
                             float* __restrict__ MEANS, unsigned short* __restrict__ ZPAGE) {
  int g = blockIdx.x, c = threadIdx.x;
  float al, be;
  if (g < 5) { al = 1.f; be = oft_b[g * 256 + c]; MEANS[g * 256 + c] = 0.f; }
  else {
    const float* gg = (g == 5) ? g1 : g2;
    const float* bb = (g == 5) ? b1 : b2;
    const float* mm = (g == 5) ? m1 : m2;
    const float* vv = (g == 5) ? v1 : v2;
    al = gg[c] / sqrtf(vv[c] + 1e-5f);
    be = bb[c] - mm[c] * al;
  }
  ALPHA[g * 256 + c] = al; BETA[g * 256 + c] = be;
  if (g == 0) ZPAGE[c] = 0;
}

// ---------------- oft weights -> tiled B (coalesced-read variant) ----------
__global__ void k_wpermT(const float* __restrict__ w, unsigned short* __restrict__ wp) {
  int b = blockIdx.x;                      // < 1280
  int sc = b >> 8, oc = b & 255;
  int t = threadIdx.x;
  const float* src = w + (size_t)b * 2304;
  int row = oc & 127, cb = oc >> 7;
  unsigned short* dst = wp + (size_t)sc * 589824 + (size_t)cb * 294912 + row * 8;
#pragma unroll
  for (int i = 0; i < 9; ++i) {
    int idx = i * 256 + t;                 // = c*9 + z
    float v = src[idx];
    int c = idx / 9, z = idx - c * 9;
    int k = z * 256 + c;
    int s = k >> 5, kc = (k >> 3) & 3, j = k & 7;
    dst[(size_t)s * 4096 + kc * 1024 + j] = f2bf(v);
  }
}

// ---------------- conv1 weights -> tiled, *satt (coalesced-read) -----------
__global__ void k_wperm1T(const float* __restrict__ w, const float* __restrict__ satt,
                          unsigned short* __restrict__ wp) {
  int oc = blockIdx.x;                     // < 256
  int t = threadIdx.x;
  const float* src = w + (size_t)oc * 11520;
  int row = oc & 127, cb = oc >> 7;
  unsigned short* dst = wp + (size_t)cb * (9 * 40 * 4096) + row * 8;
#pragma unroll
  for (int i = 0; i < 45; ++i) {
    int idx = i * 256 + t;                 // = ic*9 + r
    float v = src[idx];
    int ic = idx / 9, r = idx - ic * 9;
    int s = ic >> 5, kc = (ic >> 3) & 3, j = ic & 7;
    dst[(size_t)(r * 40 + s) * 4096 + kc * 1024 + j] = f2bf(v * satt[ic]);
  }
}

// ---------------- conv2 weights -> tiled (coalesced-read) ------------------
__global__ void k_wperm2T(const float* __restrict__ w, unsigned short* __restrict__ wp) {
  int oc = blockIdx.x;                     // < 256
  int t = threadIdx.x;
  const float* src = w + (size_t)oc * 2304;
  int row = oc & 127, cb = oc >> 7;
  unsigned short* dst = wp + (size_t)cb * (9 * 8 * 4096) + row * 8;
#pragma unroll
  for (int i = 0; i < 9; ++i) {
    int idx = i * 256 + t;                 // = ic*9 + r
    float v = src[idx];
    int ic = idx / 9, r = idx - ic * 9;
    int s = ic >> 5, kc = (ic >> 3) & 3, j = ic & 7;
    dst[(size_t)(r * 8 + s) * 4096 + kc * 1024 + j] = f2bf(v);
  }
}

// ---------------- tap table, compressed 64B records, multi-scale -----------
__global__ void k_tapsA(const float* __restrict__ calib, int* __restrict__ taps, int s0) {
  int idx = blockIdx.x * 256 + threadIdx.x;
  if (idx >= ZC * NBOX) return;
  int slab = blockIdx.y, sc = s0 + slab;
  int Hf = cHFs[sc], Wf = cWFs[sc];
  float areaScale = (float)(Hf * Wf) * 0.25f;
  int z = idx / NBOX, n = idx % NBOX;
  int d = n / 124, wj = n % 124;
  float P[12];
#pragma unroll
  for (int i = 0; i < 12; ++i) P[i] = calib[i];
  auto proj = [&](int k, int i, int j, float& nxo, float& nyo) {
    float X = 0.64f * (float)i;
    float Y = 39.68f - 0.64f * (float)j;
    float Z = 2.76f - 0.64f * (float)k;
    float hx = P[0] * X + P[1] * Y + P[2]  * Z + P[3];
    float hy = P[4] * X + P[5] * Y + P[6]  * Z + P[7];
    float hz = P[8] * X + P[9] * Y + P[10] * Z + P[11];
    float px = hx / hz, py = hy / hz;
    nxo = 2.f * px / 1280.f - 1.f; nxo = fminf(fmaxf(nxo, -1.f), 1.f);
    nyo = 2.f * py / 384.f  - 1.f; nyo = fminf(fmaxf(nyo, -1.f), 1.f);
  };
  float ax, ay, bx, by, cx, cy, dx, dy;
  proj(z,     d,     wj,     ax, ay);
  proj(z,     d + 1, wj,     bx, by);
  proj(z + 1, d + 1, wj + 1, cx, cy);
  proj(z + 1, d,     wj + 1, dx, dy);
  float x0 = fminf(ax, bx), y0 = fminf(ay, by);
  float x1 = fmaxf(cx, dx), y1 = fmaxf(cy, dy);
  float rawA = (x1 - x0) * (y1 - y0) * areaScale;
  int* ob = taps + (size_t)slab * (ZC * NBOX * TAPINTS) + (size_t)idx * TAPINTS;
  if (!(rawA > 0.f)) { ob[0] = 0; return; }
  float inv = 1.f / (rawA + 1e-6f);

  float u0 = (x0 + 1.f) * ((float)Wf * 0.5f) - 0.5f;
  float u1 = (x1 + 1.f) * ((float)Wf * 0.5f) - 0.5f;
  float fu0 = floorf(u0), fu1 = floorf(u1);
  int cx0 = (int)fu0, cx1 = (int)fu1;
  float wx0 = u0 - fu0, wx1 = u1 - fu1;
  int xs[4]; float xw[4];
  xs[0] = cx0; xs[1] = cx0 + 1; xs[2] = cx1; xs[3] = cx1 + 1;
  xw[0] = (1.f - wx0) * inv; xw[1] = wx0 * inv;
  xw[2] = -(1.f - wx1) * inv; xw[3] = -wx1 * inv;
  int dcx = cx1 - cx0;
  if (dcx == 0)      { xw[0] += xw[2]; xw[1] += xw[3]; xw[2] = 0.f; xw[3] = 0.f; }
  else if (dcx == 1) { xw[1] += xw[2]; xw[2] = xw[3]; xs[2] = xs[3]; xw[3] = 0.f; }
#pragma unroll
  for (int j = 0; j < 4; ++j) {
    if (xs[j] < 0 || xs[j] >= Wf) xw[j] = 0.f;
    xs[j] = min(max(xs[j], 0), Wf - 1);
  }
#define CSWX(a, b) { if (xw[a] == 0.f && xw[b] != 0.f) { \
    float tw = xw[a]; xw[a] = xw[b]; xw[b] = tw; \
    int ts = xs[a]; xs[a] = xs[b]; xs[b] = ts; } }
  CSWX(0, 1) CSWX(2, 3) CSWX(0, 2) CSWX(1, 3) CSWX(1, 2)
#undef CSWX
  int nx = (xw[0] != 0.f) + (xw[1] != 0.f) + (xw[2] != 0.f) + (xw[3] != 0.f);

  float v0 = (y0 + 1.f) * ((float)Hf * 0.5f) - 0.5f;
  float v1 = (y1 + 1.f) * ((float)Hf * 0.5f) - 0.5f;
  float fv0 = floorf(v0), fv1 = floorf(v1);
  int ry0 = (int)fv0, ry1 = (int)fv1;
  float wy0 = v0 - fv0, wy1 = v1 - fv1;
  int ys[4]; float yw[4];
  ys[0] = ry0; ys[1] = ry0 + 1; ys[2] = ry1; ys[3] = ry1 + 1;
  yw[0] = 1.f - wy0; yw[1] = wy0; yw[2] = -(1.f - wy1); yw[3] = -wy1;
  int dcy = ry1 - ry0;
  if (dcy == 0)      { yw[0] += yw[2]; yw[1] += yw[3]; yw[2] = 0.f; yw[3] = 0.f; }
  else if (dcy == 1) { yw[1] += yw[2]; yw[2] = yw[3]; ys[2] = ys[3]; yw[3] = 0.f; }
#pragma unroll
  for (int j = 0; j < 4; ++j) {
    if (ys[j] < 0 || ys[j] >= Hf) yw[j] = 0.f;
    ys[j] = min(max(ys[j], 0), Hf - 1);
  }
#define CSWY(a, b) { if (yw[a] == 0.f && yw[b] != 0.f) { \
    float tw = yw[a]; yw[a] = yw[b]; yw[b] = tw; \
    int ts = ys[a]; ys[a] = ys[b]; ys[b] = ts; } }
  CSWY(0, 1) CSWY(2, 3) CSWY(0, 2) CSWY(1, 3) CSWY(1, 2)
#undef CSWY
  int ny = (yw[0] != 0.f) + (yw[1] != 0.f) + (yw[2] != 0.f) + (yw[3] != 0.f);

  if (nx == 0 || ny == 0) { ob[0] = 0; return; }

  int4v* obv = (int4v*)ob;
  obv[0] = (int4v){(xs[0] << 10) | (nx << 25) | (ny << 28),
                   xs[1] << 10, xs[2] << 10, xs[3] << 10};
  obv[1] = (int4v){ys[0] * Wf * 1024, ys[1] * Wf * 1024,
                   ys[2] * Wf * 1024, ys[3] * Wf * 1024};
  float4v* wb = (float4v*)ob;
  wb[2] = (float4v){xw[0], xw[1], xw[2], xw[3]};
  wb[3] = (float4v){yw[0], yw[1], yw[2], yw[3]};
}

// ---------------- merged feats transpose: [256][S] f32 -> II [S][256] ------
__global__ void k_transpose_all(const float* __restrict__ f0, const float* __restrict__ f1,
                                const float* __restrict__ f2, const float* __restrict__ f3,
                                const float* __restrict__ f4, float* __restrict__ II) {
  int b = blockIdx.x;
  int sc, cx;
  if (b < 480)      { sc = 0; cx = b; }
  else if (b < 600) { sc = 1; cx = b - 480; }
  else if (b < 630) { sc = 2; cx = b - 600; }
  else if (b < 638) { sc = 3; cx = b - 630; }
  else              { sc = 4; cx = b - 638; }
  const int Ss[5] = {30720, 7680, 1920, 480, 120};
  const float* srcs[5] = {f0, f1, f2, f3, f4};
  int S = Ss[sc];
  const float* src = srcs[sc];
  float* dst = II + cIIof[sc];
  __shared__ float tile[64][65];
  int t = threadIdx.x;
  int wave = t >> 6, lane = t & 63;
  int s0 = cx * 64, c0 = blockIdx.y * 64;
#pragma unroll
  for (int i = 0; i < 16; ++i) {
    int c_l = wave * 16 + i;
    if (s0 + lane < S) tile[c_l][lane] = src[(size_t)(c0 + c_l) * S + s0 + lane];
  }
  __syncthreads();
#pragma unroll
  for (int i = 0; i < 16; ++i) {
    int s_l = wave * 16 + i;
    if (s0 + s_l < S) dst[(size_t)(s0 + s_l) * 256 + c0 + lane] = tile[lane][s_l];
  }
}

// ---------------- merged cumsum over w: grid 186 ---------------------------
__global__ void k_cumw_all(float* __restrict__ II) {
  int b = blockIdx.x;
  int sc, h;
  if (b < 96)       { sc = 0; h = b; }
  else if (b < 144) { sc = 1; h = b - 96; }
  else if (b < 168) { sc = 2; h = b - 144; }
  else if (b < 180) { sc = 3; h = b - 168; }
  else              { sc = 4; h = b - 180; }
  int Wf = cWFs[sc];
  float* p = II + cIIof[sc] + (size_t)h * Wf * 256 + threadIdx.x;
  float acc = 0.f;
#pragma unroll 4
  for (int w = 0; w < Wf; ++w) { acc += p[(size_t)w * 256]; p[(size_t)w * 256] = acc; }
}

// ---------------- merged cumsum over h: grid 620 ---------------------------
__global__ void k_cumh_all(float* __restrict__ II) {
  int b = blockIdx.x;
  int sc, w;
  if (b < 320)      { sc = 0; w = b; }
  else if (b < 480) { sc = 1; w = b - 320; }
  else if (b < 560) { sc = 2; w = b - 480; }
  else if (b < 600) { sc = 3; w = b - 560; }
  else              { sc = 4; w = b - 600; }
  const int Hfs[5] = {96, 48, 24, 12, 6};
  int Hf = Hfs[sc];
  size_t stride = (size_t)cWFs[sc] * 256;
  float* p = II + cIIof[sc] + (size_t)w * 256 + threadIdx.x;
  float acc = 0.f;
#pragma unroll 4
  for (int h = 0; h < Hf; ++h) { acc += p[h * stride]; p[h * stride] = acc; }
}

// ---------------- merged box sampler: all scales of a group in one launch --
// Per-dz tap s_load (round-9 form: VGPR 24, ~80% occupancy).
__global__ __launch_bounds__(512) void k_sampleA(const float* __restrict__ II,
                                                 const int* __restrict__ taps,
                                                 unsigned short* __restrict__ voxT,
                                                 int s0) {
  __shared__ unsigned short st[3][8][66][4];
  int t = threadIdx.x;
  int wave = t >> 6, lane = t & 63;
  int n = blockIdx.x * 8 + wave;
  int zg = blockIdx.y * 3;
  int slab = blockIdx.z, sc = s0 + slab;
  const float* ii = II + cIIof[sc];
  const int* tbase = taps + (size_t)slab * (ZC * NBOX * TAPINTS);
  unsigned short* vox = voxT + (size_t)slab * VOXSZ;
  const char* iib = (const char*)ii + (lane << 4);   // + c4*4 bytes
#pragma unroll
  for (int dz = 0; dz < 3; ++dz) {
    int z = zg + dz;
    const int* tb = uniform_ptr(tbase + (size_t)(z * NBOX + n) * TAPINTS);
    int xo[4], yo[4]; float xw[4], yw[4];
#pragma unroll
    for (int i = 0; i < 4; ++i) xo[i] = tb[i];        // s_load (SGPRs)
#pragma unroll
    for (int i = 0; i < 4; ++i) yo[i] = tb[4 + i];
#pragma unroll
    for (int i = 0; i < 4; ++i) xw[i] = i2f(tb[8 + i]);
#pragma unroll
    for (int i = 0; i < 4; ++i) yw[i] = i2f(tb[12 + i]);
    unsigned h = (unsigned)xo[0];
    int nx = (h >> 25) & 7;
    int ny = (h >> 28) & 7;
    xo[0] = (int)(h & 0x01FFFFFFu);
    ushort4v o;
    if (ny == 0) {                        // degenerate box: no vector loads
      o[0] = 0; o[1] = 0; o[2] = 0; o[3] = 0;
    } else {
      int o_[16]; float w_[16];
#pragma unroll
      for (int r = 0; r < 4; ++r)
#pragma unroll
        for (int c = 0; c < 4; ++c) {
          o_[r * 4 + c] = yo[r] + xo[c];             // scalar adds
          w_[r * 4 + c] = yw[r] * xw[c];
        }
      float4v a0 = {0.f, 0.f, 0.f, 0.f}, a1 = a0;
#define TAP(i, acc) { float4v t_ = *(const float4v*)(iib + (size_t)(unsigned)o_[i]); acc += t_ * w_[i]; }
      TAP(0, a0)
      if (nx > 1) TAP(1, a1)
      if (nx > 2) TAP(2, a0)
      if (nx > 3) TAP(3, a1)
      if (ny > 1) {
        TAP(4, a0)
        if (nx > 1) TAP(5, a1)
        if (nx > 2) TAP(6, a0)
        if (nx > 3) TAP(7, a1)
      }
      if (ny > 2) {
        TAP(8, a0)
        if (nx > 1) TAP(9, a1)
        if (nx > 2) TAP(10, a0)
        if (nx > 3) TAP(11, a1)
      }
      if (ny > 3) {
        TAP(12, a0)
        if (nx > 1) TAP(13, a1)
        if (nx > 2) TAP(14, a0)
        if (nx > 3) TAP(15, a1)
      }
#undef TAP
      float4v acc = a0 + a1;
#pragma unroll
      for (int j = 0; j < 4; ++j) o[j] = f2bf(acc[j]);
    }
    *(ushort4v*)&st[dz][wave][lane][0] = o;
  }
  __syncthreads();
  // cooperative write: chunk q = (zq, si); 512B contiguous, 32 lanes x 16B.
  int nb = (blockIdx.x * 8) >> 7;
  int r0 = (blockIdx.x * 8) & 127;
  unsigned short* outb = vox + (size_t)nb * NBSTRIDE + (size_t)r0 * 32;
  int lane32 = t & 31;
  int row = lane32 >> 2, kc = lane32 & 3;
#pragma unroll
  for (int p = 0; p < 2; ++p) {
    int q = p * 16 + (t >> 5);
    if (q < 24) {
      int zq = q >> 3;            // 0..2
      int si = q & 7;             // step within z
      short8 v = *(const short8*)&st[zq][row][si * 8 + kc * 2][0];
      *(short8*)(outb + (size_t)(zg + zq) * 32768 + (size_t)si * 4096
                 + (size_t)(row * 32 + kc * 8)) = v;
    }
  }
}

// ---------------- OFT GEMM, scales batched, full K=2304, 8 waves -----------
// Double-buffered LDS, single barrier per K-step (T3 minimum 2-phase).
// Fused epilogue: +beta, relu, bf16, LDS repack, per-block column means.
__global__ __launch_bounds__(512) void k_gemmT_all(
    const unsigned short* __restrict__ AT, const unsigned short* __restrict__ BT,
    const float* __restrict__ beta, unsigned short* __restrict__ xbuf,
    float* __restrict__ means, int s0) {
  __shared__ unsigned short ls[16384];  // 2 bufs x (A 4096 + B 4096) shorts
  __shared__ float lsm[128];
  int t = threadIdx.x;
  int lane = t & 63, wave = t >> 6;          // 8 waves
  int l15 = lane & 15, quad = lane >> 4;
  int nb = blockIdx.x, cb = blockIdx.y;
  int slab = blockIdx.z, sc = s0 + slab;
  int wrow = (wave & 3) * 32, wcol = (wave >> 2) * 64;

  const unsigned short* ga = AT + (size_t)slab * VOXSZ + (size_t)nb * NBSTRIDE + t * 8;
  const unsigned short* gb = BT + (size_t)sc * 589824 + (size_t)cb * NBSTRIDE + t * 8;

  float4v acc[2][4];
#pragma unroll
  for (int mi = 0; mi < 2; ++mi)
#pragma unroll
    for (int ni = 0; ni < 4; ++ni) acc[mi][ni] = (float4v){0.f, 0.f, 0.f, 0.f};

  // prologue: stage step 0 into buf0
  async16(ga, ls + t * 8);
  async16(gb, ls + 4096 + t * 8);
  ga += TILEK; gb += TILEK;
  __syncthreads();

  for (int s = 0; s < 72; ++s) {
    unsigned short* buf = ls + (s & 1) * 8192;
    if (s < 71) {
      unsigned short* nbuf = ls + ((s + 1) & 1) * 8192;
      async16(ga, nbuf + t * 8);
      async16(gb, nbuf + 4096 + t * 8);
      ga += TILEK; gb += TILEK;
    }
    short8 af[2], bf[4];
    const short8* pA = (const short8*)buf;
    const short8* pB = (const short8*)(buf + 4096);
#pragma unroll
    for (int mi = 0; mi < 2; ++mi) af[mi] = pA[(wrow + mi * 16 + l15) * 4 + quad];
#pragma unroll
    for (int ni = 0; ni < 4; ++ni) bf[ni] = pB[quad * 128 + wcol + ni * 16 + l15];
#pragma unroll
    for (int mi = 0; mi < 2; ++mi)
#pragma unroll
      for (int ni = 0; ni < 4; ++ni)
        acc[mi][ni] = __builtin_amdgcn_mfma_f32_16x16x32_bf16(af[mi], bf[ni], acc[mi][ni], 0, 0, 0);
    __syncthreads();   // drains stage(s+1) loads (covered by compute) + sync
  }

  // epilogue: beta + relu -> bf16, repack via LDS, coalesced 256B row stores
  float bval[4];
  float msum[4] = {0.f, 0.f, 0.f, 0.f};
#pragma unroll
  for (int ni = 0; ni < 4; ++ni)
    bval[ni] = beta[sc * 256 + cb * 128 + wcol + ni * 16 + l15];
#pragma unroll
  for (int ph = 0; ph < 2; ++ph) {
    if ((wrow >> 6) == ph) {
#pragma unroll
      for (int mi = 0; mi < 2; ++mi)
#pragma unroll
        for (int ni = 0; ni < 4; ++ni)
#pragma unroll
          for (int j = 0; j < 4; ++j) {
            int row = (wrow & 63) + mi * 16 + quad * 4 + j;   // 0..63 local
            int col = wcol + ni * 16 + l15;                   // 0..127
            float v = acc[mi][ni][j] + bval[ni];
            v = v > 0.f ? v : 0.f;
            ls[row * 136 + col] = f2bf(v);
            if (nb * 128 + ph * 64 + row < NBOX) msum[ni] += v;
          }
    }
    __syncthreads();
#pragma unroll
    for (int it = 0; it < 2; ++it) {
      int idx = it * 512 + t;                    // 0..1023
      int row = idx >> 4, ch = idx & 15;
      int nn = nb * 128 + ph * 64 + row;
      if (nn < NBOX) {
        short8 v = *(const short8*)&ls[row * 136 + ch * 8];
        *(short8*)(xbuf + (size_t)nn * 1280 + sc * 256 + cb * 128 + ch * 8) = v;
      }
    }
    __syncthreads();
  }
  // per-block column-sum reduction -> global means (k_att divides by NBOX)
  if (t < 128) lsm[t] = 0.f;
  __syncthreads();
#pragma unroll
  for (int ni = 0; ni < 4; ++ni)
    atomicAdd(&lsm[wcol + ni * 16 + l15], msum[ni]);
  __syncthreads();
  if (t < 128) atomicAdd(&means[sc * 256 + cb * 128 + t], lsm[t]);
}

// ---------------- OFT GEMM fallback, split-K=4: raw f32 partials -----------
__global__ __launch_bounds__(256) void k_gemmT(
    const unsigned short* __restrict__ AT, const unsigned short* __restrict__ BT,
    float* __restrict__ part) {
  __shared__ unsigned short lsA[4096];
  __shared__ unsigned short lsB[4096];
  int t = threadIdx.x;
  int lane = t & 63, wave = t >> 6;
  int l15 = lane & 15, quad = lane >> 4;
  int nb = blockIdx.x, cb = blockIdx.y, ks = blockIdx.z;
  int wrow = (wave >> 1) * 64, wcol = (wave & 1) * 64;

  const unsigned short* ga = AT + (size_t)nb * NBSTRIDE + (size_t)ks * 18 * TILEK + t * 8;
  const unsigned short* gb = BT + (size_t)cb * NBSTRIDE + (size_t)ks * 18 * TILEK + t * 8;
  unsigned short* ldA = lsA + t * 8;
  unsigned short* ldB = lsB + t * 8;

  float4v acc[4][4];
#pragma unroll
  for (int mi = 0; mi < 4; ++mi)
#pragma unroll
    for (int ni = 0; ni < 4; ++ni) acc[mi][ni] = (float4v){0.f, 0.f, 0.f, 0.f};

  for (int s = 0; s < 18; ++s) {
    async16(ga, ldA);
    async16(ga + 2048, ldA + 2048);
    async16(gb, ldB);
    async16(gb + 2048, ldB + 2048);
    ga += TILEK; gb += TILEK;
    __syncthreads();
    short8 af[4], bf[4];
    const short8* pA = (const short8*)lsA;
    const short8* pB = (const short8*)lsB;
#pragma unroll
    for (int mi = 0; mi < 4; ++mi) af[mi] = pA[(wrow + mi * 16 + l15) * 4 + quad];
#pragma unroll
    for (int ni = 0; ni < 4; ++ni) bf[ni] = pB[quad * 128 + wcol + ni * 16 + l15];
#pragma unroll
    for (int mi = 0; mi < 4; ++mi)
#pragma unroll
      for (int ni = 0; ni < 4; ++ni)
        acc[mi][ni] = __builtin_amdgcn_mfma_f32_16x16x32_bf16(af[mi], bf[ni], acc[mi][ni], 0, 0, 0);
    __syncthreads();
  }

#pragma unroll
  for (int mi = 0; mi < 4; ++mi) {
    int nb0 = nb * 128 + wrow + mi * 16 + quad * 4;
#pragma unroll
    for (int j = 0; j < 4; ++j) {
      int nn = nb0 + j;
      if (nn < NBOX) {
#pragma unroll
        for (int ni = 0; ni < 4; ++ni) {
          int oc = cb * 128 + wcol + ni * 16 + l15;
          part[((size_t)ks * NBOX + nn) * 256 + oc] = acc[mi][ni][j];
        }
      }
    }
  }
}

// reduce OFT partials -> XBUF [n][1280] @ choff (bias + relu, alpha=1)
__global__ void k_redoft(const float* __restrict__ part, const float* __restrict__ beta,
                         unsigned short* __restrict__ xbuf, int choff) {
  int n = blockIdx.x, oc = threadIdx.x;
  float v = part[(size_t)n * 256 + oc]
          + part[((size_t)NBOX + n) * 256 + oc]
          + part[((size_t)2 * NBOX + n) * 256 + oc]
          + part[((size_t)3 * NBOX + n) * 256 + oc];
  v += beta[oc];
  v = v > 0.f ? v : 0.f;
  xbuf[(size_t)n * 1280 + choff + oc] = f2bf(v);
}

// ---------------- conv GEMM, split by tap r, 8 waves, double-buffered ------
template <int MODE>
__global__ __launch_bounds__(512) void k_gemmS(
    const unsigned short* __restrict__ A, const unsigned short* __restrict__ BT,
    float* __restrict__ part, const unsigned short* __restrict__ zpage) {
  constexpr int KIC   = (MODE == 1) ? 1280 : 256;
  constexpr int STEPS = KIC / 32;
  __shared__ unsigned short ls[16384];  // 2 bufs x (A 4096 + B 4096) shorts
  int t = threadIdx.x;
  int lane = t & 63, wave = t >> 6;          // 8 waves
  int l15 = lane & 15, quad = lane >> 4;
  int n0 = blockIdx.x * 128, oc0 = blockIdx.y * 128;
  int r = blockIdx.z;
  int wrow = (wave & 3) * 32, wcol = (wave >> 2) * 64;
  int srow = t & 127, skc = t >> 7;          // skc in 0..3

  int p = n0 + srow;
  int oy = p / 54, ox = p - oy * 54;
  int ky = r / 3, kx = r - ky * 3;
  bool valid; int sp;
  if (MODE == 1) {
    int ih = 2 * oy + ky - 1, iw = 2 * ox + kx - 1;
    valid = (p < NPIX) && ((unsigned)ih < 124u) && ((unsigned)iw < 108u);
    sp = iw * 124 + ih;
  } else {
    int ih = oy + ky - 1, iw = ox + kx - 1;
    valid = (p < NPIX) && ((unsigned)ih < 62u) && ((unsigned)iw < 54u);
    sp = ih * 54 + iw;
  }
  const unsigned short* ga = valid ? (A + (size_t)sp * KIC + skc * 8) : zpage;
  int astep = valid ? 32 : 0;
  const unsigned short* gb = BT + ((size_t)(blockIdx.y * 9 + r) * STEPS) * TILEK + t * 8;

  float4v acc[2][4];
#pragma unroll
  for (int mi = 0; mi < 2; ++mi)
#pragma unroll
    for (int ni = 0; ni < 4; ++ni) acc[mi][ni] = (float4v){0.f, 0.f, 0.f, 0.f};

  // prologue: stage step 0 into buf0
  async16(ga, ls + t * 8);
  async16(gb, ls + 4096 + t * 8);
  ga += astep; gb += TILEK;
  __syncthreads();

  for (int s = 0; s < STEPS; ++s) {
    unsigned short* buf = ls + (s & 1) * 8192;
    if (s < STEPS - 1) {
      unsigned short* nbuf = ls + ((s + 1) & 1) * 8192;
      async16(ga, nbuf + t * 8);
      async16(gb, nbuf + 4096 + t * 8);
      ga += astep; gb += TILEK;
    }
    short8 af[2], bf[4];
    const short8* pA = (const short8*)buf;
    const short8* pB = (const short8*)(buf + 4096);
#pragma unroll
    for (int mi = 0; mi < 2; ++mi) af[mi] = pA[quad * 128 + wrow + mi * 16 + l15];
#pragma unroll
    for (int ni = 0; ni < 4; ++ni) bf[ni] = pB[quad * 128 + wcol + ni * 16 + l15];
#pragma unroll
    for (int mi = 0; mi < 2; ++mi)
#pragma unroll
      for (int ni = 0; ni < 4; ++ni)
        acc[mi][ni] = __builtin_amdgcn_mfma_f32_16x16x32_bf16(af[mi], bf[ni], acc[mi][ni], 0, 0, 0);
    __syncthreads();
  }

#pragma unroll
  for (int mi = 0; mi < 2; ++mi) {
    int nb0 = n0 + wrow + mi * 16 + quad * 4;
#pragma unroll
    for (int j = 0; j < 4; ++j) {
      int nn = nb0 + j;
      if (nn < NPIX) {
#pragma unroll
        for (int ni = 0; ni < 4; ++ni) {
          int oc = oc0 + wcol + ni * 16 + l15;
          part[((size_t)r * NPIX + nn) * 256 + oc] = acc[mi][ni][j];
        }
      }
    }
  }
}

// reduce conv partials (9 taps) with alpha/beta + relu
template <bool F32OUT>
__global__ void k_redconv(const float* __restrict__ part, const float* __restrict__ alpha,
                          const float* __restrict__ beta, void* __restrict__ outv) {
  int p = blockIdx.x, oc = threadIdx.x;
  float v = 0.f;
#pragma unroll
  for (int r = 0; r < 9; ++r) v += part[((size_t)r * NPIX + p) * 256 + oc];
  v = v * alpha[oc] + beta[oc];
  v = v > 0.f ? v : 0.f;
  if (F32OUT) ((float*)outv)[(size_t)oc * NPIX + p] = v;
  else ((unsigned short*)outv)[(size_t)p * 256 + oc] = f2bf(v);
}

// ---------------- channel means over XBUF (fallback path only) -------------
__global__ void k_means2(const unsigned short* __restrict__ x, float* __restrict__ means) {
  int tid = threadIdx.x;
  if (tid >= 160) return;            // 160 threads x 8 ch = 1280
  int c0 = tid * 8;
  int r0 = blockIdx.x * 64;
  float part[8] = {0.f, 0.f, 0.f, 0.f, 0.f, 0.f, 0.f, 0.f};
  for (int i = 0; i < 64; ++i) {
    int row = r0 + i;
    if (row < NBOX) {
      short8 v = *(const short8*)(x + (size_t)row * 1280 + c0);
#pragma unroll
      for (int j = 0; j < 8; ++j) part[j] += bf2f((unsigned short)v[j]);
    }
  }
#pragma unroll
  for (int j = 0; j < 8; ++j) atomicAdd(&means[c0 + j], part[j]);
}

__global__ void k_att(const float* __restrict__ means, const float* __restrict__ aw,
                      const float* __restrict__ ab, float* __restrict__ satt) {
  int sc = blockIdx.x, c = threadIdx.x;
  __shared__ float m[256];
  m[c] = means[sc * 256 + c] * (1.f / (float)NBOX);
  __syncthreads();
  float acc = ab[c];
  for (int j = 0; j < 256; ++j) acc += m[j] * aw[c * 256 + j];
  satt[sc * 256 + c] = 1.f / (1.f + expf(-acc));
}

extern "C" void kernel_launch(void* const* d_in, const int* in_sizes, int n_in,
                              void* d_out, int out_size, void* d_ws, size_t ws_size,
                              hipStream_t stream) {
  const float* feats[5];
  for (int i = 0; i < 5; ++i) feats[i] = (const float*)d_in[i];
  const float* calib   = (const float*)d_in[5];
  const float* oft_w   = (const float*)d_in[6];
  const float* oft_b   = (const float*)d_in[7];
  const float* att_w   = (const float*)d_in[8];
  const float* att_b   = (const float*)d_in[9];
  const float* conv1_w = (const float*)d_in[10];
  const float* bn1g = (const float*)d_in[11];
  const float* bn1b = (const float*)d_in[12];
  const float* bn1m = (const float*)d_in[13];
  const float* bn1v = (const float*)d_in[14];
  const float* conv2_w = (const float*)d_in[15];
  const float* bn2g = (const float*)d_in[16];
  const float* bn2b = (const float*)d_in[17];
  const float* bn2m = (const float*)d_in[18];
  const float* bn2v = (const float*)d_in[19];

  char* ws = (char*)d_ws;
  size_t off = 0;
  auto alloc = [&](size_t bytes) -> void* {
    void* p = ws + off; off += (bytes + 255) & ~(size_t)255; return p;
  };
  unsigned short* WPERMT = (unsigned short*)alloc((size_t)5 * 589824 * 2);
  unsigned short* WC1T   = (unsigned short*)alloc((size_t)2949120 * 2);
  unsigned short* WC2T   = (unsigned short*)alloc((size_t)589824 * 2);
  float*          II     = (float*)alloc((size_t)10475520 * 4);
  unsigned short* XBUF   = (unsigned short*)alloc((size_t)NBOX * 1280 * 2);
  unsigned short* Y1     = (unsigned short*)alloc((size_t)NPIX * 256 * 2);
  float*          MEANS  = (float*)alloc(1280 * 4);
  float*          SATT   = (float*)alloc(1280 * 4);
  float*          ALPHA  = (float*)alloc(7 * 256 * 4);
  float*          BETA   = (float*)alloc(7 * 256 * 4);
  unsigned short* ZPAGE  = (unsigned short*)alloc(256 * 2);

  const size_t SLAB    = (size_t)VOXSZ * 2;              // 61.9 MB per scale
  const size_t TAPSZ_C = (size_t)ZC * NBOX * 64;         // 7.7 MB per scale
  const size_t PARTSZ  = (size_t)4 * NBOX * 256 * 4;     // 54.9 MB (split-K)
  size_t rem = (ws_size > off) ? ws_size - off : 0;

  int NS, NT;             // slabs / tap-slabs; NS=0 = split-K fallback
  int* TAPS; unsigned short* VOXT; float* PART;
  if (rem >= 2 * SLAB + 5 * TAPSZ_C) {
    NT = 5;
    TAPS = (int*)alloc(5 * TAPSZ_C);
    NS = (int)((rem - 5 * TAPSZ_C) / SLAB); if (NS > 5) NS = 5;
    VOXT = (unsigned short*)alloc((size_t)NS * SLAB);
    PART = (float*)VOXT;
  } else if (rem >= 2 * (SLAB + TAPSZ_C)) {
    NT = 0;               // per-group taps
    NS = (int)(rem / (SLAB + TAPSZ_C)); if (NS > 5) NS = 5;
    TAPS = (int*)alloc((size_t)NS * TAPSZ_C);
    VOXT = (unsigned short*)alloc((size_t)NS * SLAB);
    PART = (float*)VOXT;
  } else {
    NS = 0; NT = 0;       // split-K fallback (fits in >=117 MB)
    VOXT = (unsigned short*)alloc(SLAB);
    PART = (float*)alloc(PARTSZ);
    TAPS = (int*)PART;
  }
  (void)in_sizes; (void)n_in; (void)out_size;

  k_alpha_beta<<<7, 256, 0, stream>>>(oft_b, bn1g, bn1b, bn1m, bn1v,
                                      bn2g, bn2b, bn2m, bn2v, ALPHA, BETA, MEANS, ZPAGE);
  k_wpermT<<<1280, 256, 0, stream>>>(oft_w, WPERMT);
  k_wperm2T<<<256, 256, 0, stream>>>(conv2_w, WC2T);

  k_transpose_all<<<dim3(640, 4), 256, 0, stream>>>(feats[0], feats[1], feats[2],
                                                    feats[3], feats[4], II);
  k_cumw_all<<<186, 256, 0, stream>>>(II);
  k_cumh_all<<<620, 256, 0, stream>>>(II);

  const int TGRID = (ZC * NBOX + 255) / 256;
  if (NS > 0) {
    if (NT == 5)
      k_tapsA<<<dim3(TGRID, 5), 256, 0, stream>>>(calib, TAPS, 0);
    int g0 = 0;
    while (g0 < 5) {
      int gsz = 5 - g0; if (gsz > NS) gsz = NS;
      int* tg = TAPS;
      if (NT == 5) tg = TAPS + (size_t)g0 * (ZC * NBOX * TAPINTS);
      else k_tapsA<<<dim3(TGRID, gsz), 256, 0, stream>>>(calib, TAPS, g0);
      k_sampleA<<<dim3(NBOX / 8, 3, gsz), 512, 0, stream>>>(II, tg, VOXT, g0);
      k_gemmT_all<<<dim3(NBLK0, 2, gsz), 512, 0, stream>>>(VOXT, WPERMT, BETA,
                                                           XBUF, MEANS, g0);
      g0 += gsz;
    }
  } else {
    for (int s = 0; s < 5; ++s) {
      k_tapsA<<<dim3(TGRID, 1), 256, 0, stream>>>(calib, TAPS, s);
      k_sampleA<<<dim3(NBOX / 8, 3, 1), 512, 0, stream>>>(II, TAPS, VOXT, s);
      k_gemmT<<<dim3(NBLK0, 2, 4), 256, 0, stream>>>(
          VOXT, WPERMT + (size_t)s * 589824, PART);
      k_redoft<<<NBOX, 256, 0, stream>>>(PART, BETA + s * 256, XBUF, s * 256);
    }
    k_means2<<<(NBOX + 63) / 64, 256, 0, stream>>>(XBUF, MEANS);
  }

  k_att<<<5, 256, 0, stream>>>(MEANS, att_w, att_b, SATT);
  k_wperm1T<<<256, 256, 0, stream>>>(conv1_w, SATT, WC1T);

  k_gemmS<1><<<dim3(NBLKC, 2, 9), 512, 0, stream>>>(XBUF, WC1T, PART, ZPAGE);
  k_redconv<false><<<NPIX, 256, 0, stream>>>(PART, ALPHA + 5 * 256, BETA + 5 * 256, Y1);

  k_gemmS<2><<<dim3(NBLKC, 2, 9), 512, 0, stream>>>(Y1, WC2T, PART, ZPAGE);
  k_redconv<true><<<NPIX, 256, 0, stream>>>(PART, ALPHA + 6 * 256, BETA + 6 * 256, d_out);
}

// Round 14
// 735.207 us; speedup vs baseline: 1.0213x; 1.0213x over previous
//
#include <hip/hip_runtime.h>

typedef __attribute__((ext_vector_type(8))) short short8;
typedef __attribute__((ext_vector_type(4))) float float4v;
typedef __attribute__((ext_vector_type(4))) int int4v;
typedef __attribute__((ext_vector_type(4))) unsigned short ushort4v;

#define NBOX 13392   // 108*124 bev cells (n = d*124 + wj)
#define ZC 9
#define KOFT 2304    // 9*256, k = z*256+c
#define NPIX 3348    // 62*54
#define NBLK0 105    // ceil(13392/128)
#define NBLKC 27     // ceil(3348/128)
#define TILEK 4096   // shorts per 8KB step-tile
#define NBSTRIDE 294912  // 72 steps * 4096 shorts per row-block / col-block
#define VOXSZ 30965760   // NBLK0*NBSTRIDE shorts per scale
#define TAPINTS 16       // compressed tap record: 16 ints = 64 B per box

__device__ __forceinline__ unsigned short f2bf(float f) {
  union { float f; unsigned int i; } v; v.f = f;
  unsigned int r = v.i + 0x7FFFu + ((v.i >> 16) & 1u);
  return (unsigned short)(r >> 16);
}
__device__ __forceinline__ float bf2f(unsigned short u) {
  union { unsigned int i; float f; } v; v.i = ((unsigned int)u) << 16; return v.f;
}
__device__ __forceinline__ float i2f(int i) {
  union { int i; float f; } v; v.i = i; return v.f;
}

__device__ __constant__ int cHFs[5] = {96, 48, 24, 12, 6};
__device__ __constant__ int cWFs[5] = {320, 160, 80, 40, 20};
__device__ __constant__ size_t cIIof[5] = {0, 7864320, 9830400, 10321920, 10444800};

// wave-uniform pointer: readfirstlane both halves so loads become s_load
__device__ __forceinline__ const int* uniform_ptr(const int* p) {
  unsigned lo = (unsigned)(uintptr_t)p;
  unsigned hi = (unsigned)((uintptr_t)p >> 32);
  lo = (unsigned)__builtin_amdgcn_readfirstlane((int)lo);
  hi = (unsigned)__builtin_amdgcn_readfirstlane((int)hi);
  return (const int*)(((uintptr_t)hi << 32) | (uintptr_t)lo);
}

// async 16B global->LDS (wave-uniform LDS base + lane*16)
__device__ __forceinline__ void async16(const unsigned short* g, unsigned short* l) {
  __builtin_amdgcn_global_load_lds(
      (const __attribute__((address_space(1))) unsigned int*)g,
      (__attribute__((address_space(3))) unsigned int*)l, 16, 0, 0);
}

// ---------------- alpha/beta epilogue constants + zero MEANS + zero page ---
__global__ void k_alpha_beta(const float* __restrict__ oft_b,
                             const float* __restrict__ g1, const float* __restrict__ b1,
                             const float* __restrict__ m1, const float* __restrict__ v1,
                             const float* __restrict__ g2, const float* __restrict__ b2,
                             const float* __restrict__ m2, const float* __restrict__ v2,
                             float* __restrict__ ALPHA, float* __restrict__ BETA,
                             float* __restrict__ MEANS, unsigned short* __restrict__ ZPAGE) {
  int g = blockIdx.x, c = threadIdx.x;
  float al, be;
  if (g < 5) { al = 1.f; be = oft_b[g * 256 + c]; MEANS[g * 256 + c] = 0.f; }
  else {
    const float* gg = (g == 5) ? g1 : g2;
    const float* bb = (g == 5) ? b1 : b2;
    const float* mm = (g == 5) ? m1 : m2;
    const float* vv = (g == 5) ? v1 : v2;
    al = gg[c] / sqrtf(vv[c] + 1e-5f);
    be = bb[c] - mm[c] * al;
  }
  ALPHA[g * 256 + c] = al; BETA[g * 256 + c] = be;
  if (g == 0) ZPAGE[c] = 0;
}

// ---------------- oft weights -> tiled B (coalesced-read variant) ----------
__global__ void k_wpermT(const float* __restrict__ w, unsigned short* __restrict__ wp) {
  int b = blockIdx.x;                      // < 1280
  int sc = b >> 8, oc = b & 255;
  int t = threadIdx.x;
  const float* src = w + (size_t)b * 2304;
  int row = oc & 127, cb = oc >> 7;
  unsigned short* dst = wp + (size_t)sc * 589824 + (size_t)cb * 294912 + row * 8;
#pragma unroll
  for (int i = 0; i < 9; ++i) {
    int idx = i * 256 + t;                 // = c*9 + z
    float v = src[idx];
    int c = idx / 9, z = idx - c * 9;
    int k = z * 256 + c;
    int s = k >> 5, kc = (k >> 3) & 3, j = k & 7;
    dst[(size_t)s * 4096 + kc * 1024 + j] = f2bf(v);
  }
}

// ---------------- conv1 weights -> tiled, *satt (coalesced-read) -----------
__global__ void k_wperm1T(const float* __restrict__ w, const float* __restrict__ satt,
                          unsigned short* __restrict__ wp) {
  int oc = blockIdx.x;                     // < 256
  int t = threadIdx.x;
  const float* src = w + (size_t)oc * 11520;
  int row = oc & 127, cb = oc >> 7;
  unsigned short* dst = wp + (size_t)cb * (9 * 40 * 4096) + row * 8;
#pragma unroll
  for (int i = 0; i < 45; ++i) {
    int idx = i * 256 + t;                 // = ic*9 + r
    float v = src[idx];
    int ic = idx / 9, r = idx - ic * 9;
    int s = ic >> 5, kc = (ic >> 3) & 3, j = ic & 7;
    dst[(size_t)(r * 40 + s) * 4096 + kc * 1024 + j] = f2bf(v * satt[ic]);
  }
}

// ---------------- conv2 weights -> tiled (coalesced-read) ------------------
__global__ void k_wperm2T(const float* __restrict__ w, unsigned short* __restrict__ wp) {
  int oc = blockIdx.x;                     // < 256
  int t = threadIdx.x;
  const float* src = w + (size_t)oc * 2304;
  int row = oc & 127, cb = oc >> 7;
  unsigned short* dst = wp + (size_t)cb * (9 * 8 * 4096) + row * 8;
#pragma unroll
  for (int i = 0; i < 9; ++i) {
    int idx = i * 256 + t;                 // = ic*9 + r
    float v = src[idx];
    int ic = idx / 9, r = idx - ic * 9;
    int s = ic >> 5, kc = (ic >> 3) & 3, j = ic & 7;
    dst[(size_t)(r * 8 + s) * 4096 + kc * 1024 + j] = f2bf(v);
  }
}

// ---------------- tap table, compressed 64B records, multi-scale -----------
__global__ void k_tapsA(const float* __restrict__ calib, int* __restrict__ taps, int s0) {
  int idx = blockIdx.x * 256 + threadIdx.x;
  if (idx >= ZC * NBOX) return;
  int slab = blockIdx.y, sc = s0 + slab;
  int Hf = cHFs[sc], Wf = cWFs[sc];
  float areaScale = (float)(Hf * Wf) * 0.25f;
  int z = idx / NBOX, n = idx % NBOX;
  int d = n / 124, wj = n % 124;
  float P[12];
#pragma unroll
  for (int i = 0; i < 12; ++i) P[i] = calib[i];
  auto proj = [&](int k, int i, int j, float& nxo, float& nyo) {
    float X = 0.64f * (float)i;
    float Y = 39.68f - 0.64f * (float)j;
    float Z = 2.76f - 0.64f * (float)k;
    float hx = P[0] * X + P[1] * Y + P[2]  * Z + P[3];
    float hy = P[4] * X + P[5] * Y + P[6]  * Z + P[7];
    float hz = P[8] * X + P[9] * Y + P[10] * Z + P[11];
    float px = hx / hz, py = hy / hz;
    nxo = 2.f * px / 1280.f - 1.f; nxo = fminf(fmaxf(nxo, -1.f), 1.f);
    nyo = 2.f * py / 384.f  - 1.f; nyo = fminf(fmaxf(nyo, -1.f), 1.f);
  };
  float ax, ay, bx, by, cx, cy, dx, dy;
  proj(z,     d,     wj,     ax, ay);
  proj(z,     d + 1, wj,     bx, by);
  proj(z + 1, d + 1, wj + 1, cx, cy);
  proj(z + 1, d,     wj + 1, dx, dy);
  float x0 = fminf(ax, bx), y0 = fminf(ay, by);
  float x1 = fmaxf(cx, dx), y1 = fmaxf(cy, dy);
  float rawA = (x1 - x0) * (y1 - y0) * areaScale;
  int* ob = taps + (size_t)slab * (ZC * NBOX * TAPINTS) + (size_t)idx * TAPINTS;
  if (!(rawA > 0.f)) { ob[0] = 0; return; }
  float inv = 1.f / (rawA + 1e-6f);

  float u0 = (x0 + 1.f) * ((float)Wf * 0.5f) - 0.5f;
  float u1 = (x1 + 1.f) * ((float)Wf * 0.5f) - 0.5f;
  float fu0 = floorf(u0), fu1 = floorf(u1);
  int cx0 = (int)fu0, cx1 = (int)fu1;
  float wx0 = u0 - fu0, wx1 = u1 - fu1;
  int xs[4]; float xw[4];
  xs[0] = cx0; xs[1] = cx0 + 1; xs[2] = cx1; xs[3] = cx1 + 1;
  xw[0] = (1.f - wx0) * inv; xw[1] = wx0 * inv;
  xw[2] = -(1.f - wx1) * inv; xw[3] = -wx1 * inv;
  int dcx = cx1 - cx0;
  if (dcx == 0)      { xw[0] += xw[2]; xw[1] += xw[3]; xw[2] = 0.f; xw[3] = 0.f; }
  else if (dcx == 1) { xw[1] += xw[2]; xw[2] = xw[3]; xs[2] = xs[3]; xw[3] = 0.f; }
#pragma unroll
  for (int j = 0; j < 4; ++j) {
    if (xs[j] < 0 || xs[j] >= Wf) xw[j] = 0.f;
    xs[j] = min(max(xs[j], 0), Wf - 1);
  }
#define CSWX(a, b) { if (xw[a] == 0.f && xw[b] != 0.f) { \
    float tw = xw[a]; xw[a] = xw[b]; xw[b] = tw; \
    int ts = xs[a]; xs[a] = xs[b]; xs[b] = ts; } }
  CSWX(0, 1) CSWX(2, 3) CSWX(0, 2) CSWX(1, 3) CSWX(1, 2)
#undef CSWX
  int nx = (xw[0] != 0.f) + (xw[1] != 0.f) + (xw[2] != 0.f) + (xw[3] != 0.f);

  float v0 = (y0 + 1.f) * ((float)Hf * 0.5f) - 0.5f;
  float v1 = (y1 + 1.f) * ((float)Hf * 0.5f) - 0.5f;
  float fv0 = floorf(v0), fv1 = floorf(v1);
  int ry0 = (int)fv0, ry1 = (int)fv1;
  float wy0 = v0 - fv0, wy1 = v1 - fv1;
  int ys[4]; float yw[4];
  ys[0] = ry0; ys[1] = ry0 + 1; ys[2] = ry1; ys[3] = ry1 + 1;
  yw[0] = 1.f - wy0; yw[1] = wy0; yw[2] = -(1.f - wy1); yw[3] = -wy1;
  int dcy = ry1 - ry0;
  if (dcy == 0)      { yw[0] += yw[2]; yw[1] += yw[3]; yw[2] = 0.f; yw[3] = 0.f; }
  else if (dcy == 1) { yw[1] += yw[2]; yw[2] = yw[3]; ys[2] = ys[3]; yw[3] = 0.f; }
#pragma unroll
  for (int j = 0; j < 4; ++j) {
    if (ys[j] < 0 || ys[j] >= Hf) yw[j] = 0.f;
    ys[j] = min(max(ys[j], 0), Hf - 1);
  }
#define CSWY(a, b) { if (yw[a] == 0.f && yw[b] != 0.f) { \
    float tw = yw[a]; yw[a] = yw[b]; yw[b] = tw; \
    int ts = ys[a]; ys[a] = ys[b]; ys[b] = ts; } }
  CSWY(0, 1) CSWY(2, 3) CSWY(0, 2) CSWY(1, 3) CSWY(1, 2)
#undef CSWY
  int ny = (yw[0] != 0.f) + (yw[1] != 0.f) + (yw[2] != 0.f) + (yw[3] != 0.f);

  if (nx == 0 || ny == 0) { ob[0] = 0; return; }

  int4v* obv = (int4v*)ob;
  obv[0] = (int4v){(xs[0] << 10) | (nx << 25) | (ny << 28),
                   xs[1] << 10, xs[2] << 10, xs[3] << 10};
  obv[1] = (int4v){ys[0] * Wf * 1024, ys[1] * Wf * 1024,
                   ys[2] * Wf * 1024, ys[3] * Wf * 1024};
  float4v* wb = (float4v*)ob;
  wb[2] = (float4v){xw[0], xw[1], xw[2], xw[3]};
  wb[3] = (float4v){yw[0], yw[1], yw[2], yw[3]};
}

// ---------------- merged feats transpose: [256][S] f32 -> II [S][256] ------
__global__ void k_transpose_all(const float* __restrict__ f0, const float* __restrict__ f1,
                                const float* __restrict__ f2, const float* __restrict__ f3,
                                const float* __restrict__ f4, float* __restrict__ II) {
  int b = blockIdx.x;
  int sc, cx;
  if (b < 480)      { sc = 0; cx = b; }
  else if (b < 600) { sc = 1; cx = b - 480; }
  else if (b < 630) { sc = 2; cx = b - 600; }
  else if (b < 638) { sc = 3; cx = b - 630; }
  else              { sc = 4; cx = b - 638; }
  const int Ss[5] = {30720, 7680, 1920, 480, 120};
  const float* srcs[5] = {f0, f1, f2, f3, f4};
  int S = Ss[sc];
  const float* src = srcs[sc];
  float* dst = II + cIIof[sc];
  __shared__ float tile[64][65];
  int t = threadIdx.x;
  int wave = t >> 6, lane = t & 63;
  int s0 = cx * 64, c0 = blockIdx.y * 64;
#pragma unroll
  for (int i = 0; i < 16; ++i) {
    int c_l = wave * 16 + i;
    if (s0 + lane < S) tile[c_l][lane] = src[(size_t)(c0 + c_l) * S + s0 + lane];
  }
  __syncthreads();
#pragma unroll
  for (int i = 0; i < 16; ++i) {
    int s_l = wave * 16 + i;
    if (s0 + s_l < S) dst[(size_t)(s0 + s_l) * 256 + c0 + lane] = tile[lane][s_l];
  }
}

// ---------------- merged cumsum over w: grid 186 ---------------------------
__global__ void k_cumw_all(float* __restrict__ II) {
  int b = blockIdx.x;
  int sc, h;
  if (b < 96)       { sc = 0; h = b; }
  else if (b < 144) { sc = 1; h = b - 96; }
  else if (b < 168) { sc = 2; h = b - 144; }
  else if (b < 180) { sc = 3; h = b - 168; }
  else              { sc = 4; h = b - 180; }
  int Wf = cWFs[sc];
  float* p = II + cIIof[sc] + (size_t)h * Wf * 256 + threadIdx.x;
  float acc = 0.f;
#pragma unroll 4
  for (int w = 0; w < Wf; ++w) { acc += p[(size_t)w * 256]; p[(size_t)w * 256] = acc; }
}

// ---------------- merged cumsum over h: grid 620 ---------------------------
__global__ void k_cumh_all(float* __restrict__ II) {
  int b = blockIdx.x;
  int sc, w;
  if (b < 320)      { sc = 0; w = b; }
  else if (b < 480) { sc = 1; w = b - 320; }
  else if (b < 560) { sc = 2; w = b - 480; }
  else if (b < 600) { sc = 3; w = b - 560; }
  else              { sc = 4; w = b - 600; }
  const int Hfs[5] = {96, 48, 24, 12, 6};
  int Hf = Hfs[sc];
  size_t stride = (size_t)cWFs[sc] * 256;
  float* p = II + cIIof[sc] + (size_t)w * 256 + threadIdx.x;
  float acc = 0.f;
#pragma unroll 4
  for (int h = 0; h < Hf; ++h) { acc += p[h * stride]; p[h * stride] = acc; }
}

// ---------------- merged box sampler: all scales of a group in one launch --
__global__ __launch_bounds__(512) void k_sampleA(const float* __restrict__ II,
                                                 const int* __restrict__ taps,
                                                 unsigned short* __restrict__ voxT,
                                                 int s0) {
  __shared__ unsigned short st[3][8][66][4];
  int t = threadIdx.x;
  int wave = t >> 6, lane = t & 63;
  int n = blockIdx.x * 8 + wave;
  int zg = blockIdx.y * 3;
  int slab = blockIdx.z, sc = s0 + slab;
  const float* ii = II + cIIof[sc];
  const int* tbase = taps + (size_t)slab * (ZC * NBOX * TAPINTS);
  unsigned short* vox = voxT + (size_t)slab * VOXSZ;
  const char* iib = (const char*)ii + (lane << 4);   // + c4*4 bytes
#pragma unroll
  for (int dz = 0; dz < 3; ++dz) {
    int z = zg + dz;
    const int* tb = uniform_ptr(tbase + (size_t)(z * NBOX + n) * TAPINTS);
    int xo[4], yo[4]; float xw[4], yw[4];
#pragma unroll
    for (int i = 0; i < 4; ++i) xo[i] = tb[i];        // s_load (SGPRs)
#pragma unroll
    for (int i = 0; i < 4; ++i) yo[i] = tb[4 + i];
#pragma unroll
    for (int i = 0; i < 4; ++i) xw[i] = i2f(tb[8 + i]);
#pragma unroll
    for (int i = 0; i < 4; ++i) yw[i] = i2f(tb[12 + i]);
    unsigned h = (unsigned)xo[0];
    int nx = (h >> 25) & 7;
    int ny = (h >> 28) & 7;
    xo[0] = (int)(h & 0x01FFFFFFu);
    ushort4v o;
    if (ny == 0) {                        // degenerate box: no vector loads
      o[0] = 0; o[1] = 0; o[2] = 0; o[3] = 0;
    } else {
      int o_[16]; float w_[16];
#pragma unroll
      for (int r = 0; r < 4; ++r)
#pragma unroll
        for (int c = 0; c < 4; ++c) {
          o_[r * 4 + c] = yo[r] + xo[c];             // scalar adds
          w_[r * 4 + c] = yw[r] * xw[c];
        }
      float4v a0 = {0.f, 0.f, 0.f, 0.f}, a1 = a0;
#define TAP(i, acc) { float4v t_ = *(const float4v*)(iib + (size_t)(unsigned)o_[i]); acc += t_ * w_[i]; }
      TAP(0, a0)
      if (nx > 1) TAP(1, a1)
      if (nx > 2) TAP(2, a0)
      if (nx > 3) TAP(3, a1)
      if (ny > 1) {
        TAP(4, a0)
        if (nx > 1) TAP(5, a1)
        if (nx > 2) TAP(6, a0)
        if (nx > 3) TAP(7, a1)
      }
      if (ny > 2) {
        TAP(8, a0)
        if (nx > 1) TAP(9, a1)
        if (nx > 2) TAP(10, a0)
        if (nx > 3) TAP(11, a1)
      }
      if (ny > 3) {
        TAP(12, a0)
        if (nx > 1) TAP(13, a1)
        if (nx > 2) TAP(14, a0)
        if (nx > 3) TAP(15, a1)
      }
#undef TAP
      float4v acc = a0 + a1;
#pragma unroll
      for (int j = 0; j < 4; ++j) o[j] = f2bf(acc[j]);
    }
    *(ushort4v*)&st[dz][wave][lane][0] = o;
  }
  __syncthreads();
  // cooperative write: chunk q = (zq, si); 512B contiguous, 32 lanes x 16B.
  int nb = (blockIdx.x * 8) >> 7;
  int r0 = (blockIdx.x * 8) & 127;
  unsigned short* outb = vox + (size_t)nb * NBSTRIDE + (size_t)r0 * 32;
  int lane32 = t & 31;
  int row = lane32 >> 2, kc = lane32 & 3;
#pragma unroll
  for (int p = 0; p < 2; ++p) {
    int q = p * 16 + (t >> 5);
    if (q < 24) {
      int zq = q >> 3;            // 0..2
      int si = q & 7;             // step within z
      short8 v = *(const short8*)&st[zq][row][si * 8 + kc * 2][0];
      *(short8*)(outb + (size_t)(zg + zq) * 32768 + (size_t)si * 4096
                 + (size_t)(row * 32 + kc * 8)) = v;
    }
  }
}

// ---------------- OFT GEMM, scales batched, full K=2304, 8 waves -----------
// A (slab) step-tile layout [row128][kc4][j8]; B layout [kc4][row128][j8].
// 512 threads: wave -> 32x64 sub-tile (acc[2][4]).
// Fused epilogue: +beta, relu, bf16, LDS repack, per-block column means.
__global__ __launch_bounds__(512) void k_gemmT_all(
    const unsigned short* __restrict__ AT, const unsigned short* __restrict__ BT,
    const float* __restrict__ beta, unsigned short* __restrict__ xbuf,
    float* __restrict__ means, int s0) {
  __shared__ unsigned short ls[8704];   // A[0:4096) B[4096:8192); epilogue [64][136]
  __shared__ float lsm[128];
  unsigned short* lsA = ls;
  unsigned short* lsB = ls + 4096;
  int t = threadIdx.x;
  int lane = t & 63, wave = t >> 6;          // 8 waves
  int l15 = lane & 15, quad = lane >> 4;
  int nb = blockIdx.x, cb = blockIdx.y;
  int slab = blockIdx.z, sc = s0 + slab;
  int wrow = (wave & 3) * 32, wcol = (wave >> 2) * 64;

  const unsigned short* ga = AT + (size_t)slab * VOXSZ + (size_t)nb * NBSTRIDE + t * 8;
  const unsigned short* gb = BT + (size_t)sc * 589824 + (size_t)cb * NBSTRIDE + t * 8;
  unsigned short* ldA = lsA + t * 8;
  unsigned short* ldB = lsB + t * 8;

  float4v acc[2][4];
#pragma unroll
  for (int mi = 0; mi < 2; ++mi)
#pragma unroll
    for (int ni = 0; ni < 4; ++ni) acc[mi][ni] = (float4v){0.f, 0.f, 0.f, 0.f};

  for (int s = 0; s < 72; ++s) {
    async16(ga, ldA);
    async16(gb, ldB);
    ga += TILEK; gb += TILEK;
    __syncthreads();
    short8 af[2], bf[4];
    const short8* pA = (const short8*)lsA;
    const short8* pB = (const short8*)lsB;
#pragma unroll
    for (int mi = 0; mi < 2; ++mi) af[mi] = pA[(wrow + mi * 16 + l15) * 4 + quad];
#pragma unroll
    for (int ni = 0; ni < 4; ++ni) bf[ni] = pB[quad * 128 + wcol + ni * 16 + l15];
#pragma unroll
    for (int mi = 0; mi < 2; ++mi)
#pragma unroll
      for (int ni = 0; ni < 4; ++ni)
        acc[mi][ni] = __builtin_amdgcn_mfma_f32_16x16x32_bf16(af[mi], bf[ni], acc[mi][ni], 0, 0, 0);
    __syncthreads();
  }

  // epilogue: beta + relu -> bf16, repack via LDS, coalesced 256B row stores
  float bval[4];
  float msum[4] = {0.f, 0.f, 0.f, 0.f};
#pragma unroll
  for (int ni = 0; ni < 4; ++ni)
    bval[ni] = beta[sc * 256 + cb * 128 + wcol + ni * 16 + l15];
#pragma unroll
  for (int ph = 0; ph < 2; ++ph) {
    if ((wrow >> 6) == ph) {
#pragma unroll
      for (int mi = 0; mi < 2; ++mi)
#pragma unroll
        for (int ni = 0; ni < 4; ++ni)
#pragma unroll
          for (int j = 0; j < 4; ++j) {
            int row = (wrow & 63) + mi * 16 + quad * 4 + j;   // 0..63 local
            int col = wcol + ni * 16 + l15;                   // 0..127
            float v = acc[mi][ni][j] + bval[ni];
            v = v > 0.f ? v : 0.f;
            ls[row * 136 + col] = f2bf(v);
            if (nb * 128 + ph * 64 + row < NBOX) msum[ni] += v;
          }
    }
    __syncthreads();
#pragma unroll
    for (int it = 0; it < 2; ++it) {
      int idx = it * 512 + t;                    // 0..1023
      int row = idx >> 4, ch = idx & 15;
      int nn = nb * 128 + ph * 64 + row;
      if (nn < NBOX) {
        short8 v = *(const short8*)&ls[row * 136 + ch * 8];
        *(short8*)(xbuf + (size_t)nn * 1280 + sc * 256 + cb * 128 + ch * 8) = v;
      }
    }
    __syncthreads();
  }
  // per-block column-sum reduction -> global means (k_att divides by NBOX)
  if (t < 128) lsm[t] = 0.f;
  __syncthreads();
#pragma unroll
  for (int ni = 0; ni < 4; ++ni)
    atomicAdd(&lsm[wcol + ni * 16 + l15], msum[ni]);
  __syncthreads();
  if (t < 128) atomicAdd(&means[sc * 256 + cb * 128 + t], lsm[t]);
}

// ---------------- OFT GEMM fallback, split-K=4: raw f32 partials -----------
__global__ __launch_bounds__(256) void k_gemmT(
    const unsigned short* __restrict__ AT, const unsigned short* __restrict__ BT,
    float* __restrict__ part) {
  __shared__ unsigned short lsA[4096];
  __shared__ unsigned short lsB[4096];
  int t = threadIdx.x;
  int lane = t & 63, wave = t >> 6;
  int l15 = lane & 15, quad = lane >> 4;
  int nb = blockIdx.x, cb = blockIdx.y, ks = blockIdx.z;
  int wrow = (wave >> 1) * 64, wcol = (wave & 1) * 64;

  const unsigned short* ga = AT + (size_t)nb * NBSTRIDE + (size_t)ks * 18 * TILEK + t * 8;
  const unsigned short* gb = BT + (size_t)cb * NBSTRIDE + (size_t)ks * 18 * TILEK + t * 8;
  unsigned short* ldA = lsA + t * 8;
  unsigned short* ldB = lsB + t * 8;

  float4v acc[4][4];
#pragma unroll
  for (int mi = 0; mi < 4; ++mi)
#pragma unroll
    for (int ni = 0; ni < 4; ++ni) acc[mi][ni] = (float4v){0.f, 0.f, 0.f, 0.f};

  for (int s = 0; s < 18; ++s) {
    async16(ga, ldA);
    async16(ga + 2048, ldA + 2048);
    async16(gb, ldB);
    async16(gb + 2048, ldB + 2048);
    ga += TILEK; gb += TILEK;
    __syncthreads();
    short8 af[4], bf[4];
    const short8* pA = (const short8*)lsA;
    const short8* pB = (const short8*)lsB;
#pragma unroll
    for (int mi = 0; mi < 4; ++mi) af[mi] = pA[(wrow + mi * 16 + l15) * 4 + quad];
#pragma unroll
    for (int ni = 0; ni < 4; ++ni) bf[ni] = pB[quad * 128 + wcol + ni * 16 + l15];
#pragma unroll
    for (int mi = 0; mi < 4; ++mi)
#pragma unroll
      for (int ni = 0; ni < 4; ++ni)
        acc[mi][ni] = __builtin_amdgcn_mfma_f32_16x16x32_bf16(af[mi], bf[ni], acc[mi][ni], 0, 0, 0);
    __syncthreads();
  }

#pragma unroll
  for (int mi = 0; mi < 4; ++mi) {
    int nb0 = nb * 128 + wrow + mi * 16 + quad * 4;
#pragma unroll
    for (int j = 0; j < 4; ++j) {
      int nn = nb0 + j;
      if (nn < NBOX) {
#pragma unroll
        for (int ni = 0; ni < 4; ++ni) {
          int oc = cb * 128 + wcol + ni * 16 + l15;
          part[((size_t)ks * NBOX + nn) * 256 + oc] = acc[mi][ni][j];
        }
      }
    }
  }
}

// reduce OFT partials -> XBUF [n][1280] @ choff (bias + relu, alpha=1)
__global__ void k_redoft(const float* __restrict__ part, const float* __restrict__ beta,
                         unsigned short* __restrict__ xbuf, int choff) {
  int n = blockIdx.x, oc = threadIdx.x;
  float v = part[(size_t)n * 256 + oc]
          + part[((size_t)NBOX + n) * 256 + oc]
          + part[((size_t)2 * NBOX + n) * 256 + oc]
          + part[((size_t)3 * NBOX + n) * 256 + oc];
  v += beta[oc];
  v = v > 0.f ? v : 0.f;
  xbuf[(size_t)n * 1280 + choff + oc] = f2bf(v);
}

// ---------------- conv GEMM, split by tap r, 8 waves: raw f32 partials -----
template <int MODE>
__global__ __launch_bounds__(512) void k_gemmS(
    const unsigned short* __restrict__ A, const unsigned short* __restrict__ BT,
    float* __restrict__ part, const unsigned short* __restrict__ zpage) {
  constexpr int KIC   = (MODE == 1) ? 1280 : 256;
  constexpr int STEPS = KIC / 32;
  __shared__ unsigned short lsA[4096];
  __shared__ unsigned short lsB[4096];
  int t = threadIdx.x;
  int lane = t & 63, wave = t >> 6;          // 8 waves
  int l15 = lane & 15, quad = lane >> 4;
  int n0 = blockIdx.x * 128, oc0 = blockIdx.y * 128;
  int r = blockIdx.z;
  int wrow = (wave & 3) * 32, wcol = (wave >> 2) * 64;
  int srow = t & 127, skc = t >> 7;          // skc in 0..3

  int p = n0 + srow;
  int oy = p / 54, ox = p - oy * 54;
  int ky = r / 3, kx = r - ky * 3;
  bool valid; int sp;
  if (MODE == 1) {
    int ih = 2 * oy + ky - 1, iw = 2 * ox + kx - 1;
    valid = (p < NPIX) && ((unsigned)ih < 124u) && ((unsigned)iw < 108u);
    sp = iw * 124 + ih;
  } else {
    int ih = oy + ky - 1, iw = ox + kx - 1;
    valid = (p < NPIX) && ((unsigned)ih < 62u) && ((unsigned)iw < 54u);
    sp = ih * 54 + iw;
  }
  const unsigned short* ga = valid ? (A + (size_t)sp * KIC + skc * 8) : zpage;
  int astep = valid ? 32 : 0;
  const unsigned short* gb = BT + ((size_t)(blockIdx.y * 9 + r) * STEPS) * TILEK + t * 8;
  unsigned short* ldA = lsA + t * 8;         // LDS A layout [kc4][row128][j8]
  unsigned short* ldB = lsB + t * 8;

  float4v acc[2][4];
#pragma unroll
  for (int mi = 0; mi < 2; ++mi)
#pragma unroll
    for (int ni = 0; ni < 4; ++ni) acc[mi][ni] = (float4v){0.f, 0.f, 0.f, 0.f};

  for (int s = 0; s < STEPS; ++s) {
    async16(ga, ldA);
    async16(gb, ldB);
    ga += astep; gb += TILEK;
    __syncthreads();
    short8 af[2], bf[4];
    const short8* pA = (const short8*)lsA;
    const short8* pB = (const short8*)lsB;
#pragma unroll
    for (int mi = 0; mi < 2; ++mi) af[mi] = pA[quad * 128 + wrow + mi * 16 + l15];
#pragma unroll
    for (int ni = 0; ni < 4; ++ni) bf[ni] = pB[quad * 128 + wcol + ni * 16 + l15];
#pragma unroll
    for (int mi = 0; mi < 2; ++mi)
#pragma unroll
      for (int ni = 0; ni < 4; ++ni)
        acc[mi][ni] = __builtin_amdgcn_mfma_f32_16x16x32_bf16(af[mi], bf[ni], acc[mi][ni], 0, 0, 0);
    __syncthreads();
  }

#pragma unroll
  for (int mi = 0; mi < 2; ++mi) {
    int nb0 = n0 + wrow + mi * 16 + quad * 4;
#pragma unroll
    for (int j = 0; j < 4; ++j) {
      int nn = nb0 + j;
      if (nn < NPIX) {
#pragma unroll
        for (int ni = 0; ni < 4; ++ni) {
          int oc = oc0 + wcol + ni * 16 + l15;
          part[((size_t)r * NPIX + nn) * 256 + oc] = acc[mi][ni][j];
        }
      }
    }
  }
}

// reduce conv partials (9 taps) with alpha/beta + relu
template <bool F32OUT>
__global__ void k_redconv(const float* __restrict__ part, const float* __restrict__ alpha,
                          const float* __restrict__ beta, void* __restrict__ outv) {
  int p = blockIdx.x, oc = threadIdx.x;
  float v = 0.f;
#pragma unroll
  for (int r = 0; r < 9; ++r) v += part[((size_t)r * NPIX + p) * 256 + oc];
  v = v * alpha[oc] + beta[oc];
  v = v > 0.f ? v : 0.f;
  if (F32OUT) ((float*)outv)[(size_t)oc * NPIX + p] = v;
  else ((unsigned short*)outv)[(size_t)p * 256 + oc] = f2bf(v);
}

// ---------------- channel means over XBUF (fallback path only) -------------
__global__ void k_means2(const unsigned short* __restrict__ x, float* __restrict__ means) {
  int tid = threadIdx.x;
  if (tid >= 160) return;            // 160 threads x 8 ch = 1280
  int c0 = tid * 8;
  int r0 = blockIdx.x * 64;
  float part[8] = {0.f, 0.f, 0.f, 0.f, 0.f, 0.f, 0.f, 0.f};
  for (int i = 0; i < 64; ++i) {
    int row = r0 + i;
    if (row < NBOX) {
      short8 v = *(const short8*)(x + (size_t)row * 1280 + c0);
#pragma unroll
      for (int j = 0; j < 8; ++j) part[j] += bf2f((unsigned short)v[j]);
    }
  }
#pragma unroll
  for (int j = 0; j < 8; ++j) atomicAdd(&means[c0 + j], part[j]);
}

__global__ void k_att(const float* __restrict__ means, const float* __restrict__ aw,
                      const float* __restrict__ ab, float* __restrict__ satt) {
  int sc = blockIdx.x, c = threadIdx.x;
  __shared__ float m[256];
  m[c] = means[sc * 256 + c] * (1.f / (float)NBOX);
  __syncthreads();
  float acc = ab[c];
  for (int j = 0; j < 256; ++j) acc += m[j] * aw[c * 256 + j];
  satt[sc * 256 + c] = 1.f / (1.f + expf(-acc));
}

extern "C" void kernel_launch(void* const* d_in, const int* in_sizes, int n_in,
                              void* d_out, int out_size, void* d_ws, size_t ws_size,
                              hipStream_t stream) {
  const float* feats[5];
  for (int i = 0; i < 5; ++i) feats[i] = (const float*)d_in[i];
  const float* calib   = (const float*)d_in[5];
  const float* oft_w   = (const float*)d_in[6];
  const float* oft_b   = (const float*)d_in[7];
  const float* att_w   = (const float*)d_in[8];
  const float* att_b   = (const float*)d_in[9];
  const float* conv1_w = (const float*)d_in[10];
  const float* bn1g = (const float*)d_in[11];
  const float* bn1b = (const float*)d_in[12];
  const float* bn1m = (const float*)d_in[13];
  const float* bn1v = (const float*)d_in[14];
  const float* conv2_w = (const float*)d_in[15];
  const float* bn2g = (const float*)d_in[16];
  const float* bn2b = (const float*)d_in[17];
  const float* bn2m = (const float*)d_in[18];
  const float* bn2v = (const float*)d_in[19];

  char* ws = (char*)d_ws;
  size_t off = 0;
  auto alloc = [&](size_t bytes) -> void* {
    void* p = ws + off; off += (bytes + 255) & ~(size_t)255; return p;
  };
  unsigned short* WPERMT = (unsigned short*)alloc((size_t)5 * 589824 * 2);
  unsigned short* WC1T   = (unsigned short*)alloc((size_t)2949120 * 2);
  unsigned short* WC2T   = (unsigned short*)alloc((size_t)589824 * 2);
  float*          II     = (float*)alloc((size_t)10475520 * 4);
  unsigned short* XBUF   = (unsigned short*)alloc((size_t)NBOX * 1280 * 2);
  unsigned short* Y1     = (unsigned short*)alloc((size_t)NPIX * 256 * 2);
  float*          MEANS  = (float*)alloc(1280 * 4);
  float*          SATT   = (float*)alloc(1280 * 4);
  float*          ALPHA  = (float*)alloc(7 * 256 * 4);
  float*          BETA   = (float*)alloc(7 * 256 * 4);
  unsigned short* ZPAGE  = (unsigned short*)alloc(256 * 2);

  const size_t SLAB    = (size_t)VOXSZ * 2;              // 61.9 MB per scale
  const size_t TAPSZ_C = (size_t)ZC * NBOX * 64;         // 7.7 MB per scale
  const size_t PARTSZ  = (size_t)4 * NBOX * 256 * 4;     // 54.9 MB (split-K)
  size_t rem = (ws_size > off) ? ws_size - off : 0;

  int NS, NT;             // slabs / tap-slabs; NS=0 = split-K fallback
  int* TAPS; unsigned short* VOXT; float* PART;
  if (rem >= 2 * SLAB + 5 * TAPSZ_C) {
    NT = 5;
    TAPS = (int*)alloc(5 * TAPSZ_C);
    NS = (int)((rem - 5 * TAPSZ_C) / SLAB); if (NS > 5) NS = 5;
    VOXT = (unsigned short*)alloc((size_t)NS * SLAB);
    PART = (float*)VOXT;
  } else if (rem >= 2 * (SLAB + TAPSZ_C)) {
    NT = 0;               // per-group taps
    NS = (int)(rem / (SLAB + TAPSZ_C)); if (NS > 5) NS = 5;
    TAPS = (int*)alloc((size_t)NS * TAPSZ_C);
    VOXT = (unsigned short*)alloc((size_t)NS * SLAB);
    PART = (float*)VOXT;
  } else {
    NS = 0; NT = 0;       // split-K fallback (fits in >=117 MB)
    VOXT = (unsigned short*)alloc(SLAB);
    PART = (float*)alloc(PARTSZ);
    TAPS = (int*)PART;
  }
  (void)in_sizes; (void)n_in; (void)out_size;

  k_alpha_beta<<<7, 256, 0, stream>>>(oft_b, bn1g, bn1b, bn1m, bn1v,
                                      bn2g, bn2b, bn2m, bn2v, ALPHA, BETA, MEANS, ZPAGE);
  k_wpermT<<<1280, 256, 0, stream>>>(oft_w, WPERMT);
  k_wperm2T<<<256, 256, 0, stream>>>(conv2_w, WC2T);

  k_transpose_all<<<dim3(640, 4), 256, 0, stream>>>(feats[0], feats[1], feats[2],
                                                    feats[3], feats[4], II);
  k_cumw_all<<<186, 256, 0, stream>>>(II);
  k_cumh_all<<<620, 256, 0, stream>>>(II);

  const int TGRID = (ZC * NBOX + 255) / 256;
  if (NS > 0) {
    if (NT == 5)
      k_tapsA<<<dim3(TGRID, 5), 256, 0, stream>>>(calib, TAPS, 0);
    int g0 = 0;
    while (g0 < 5) {
      int gsz = 5 - g0; if (gsz > NS) gsz = NS;
      int* tg = TAPS;
      if (NT == 5) tg = TAPS + (size_t)g0 * (ZC * NBOX * TAPINTS);
      else k_tapsA<<<dim3(TGRID, gsz), 256, 0, stream>>>(calib, TAPS, g0);
      k_sampleA<<<dim3(NBOX / 8, 3, gsz), 512, 0, stream>>>(II, tg, VOXT, g0);
      k_gemmT_all<<<dim3(NBLK0, 2, gsz), 512, 0, stream>>>(VOXT, WPERMT, BETA,
                                                           XBUF, MEANS, g0);
      g0 += gsz;
    }
  } else {
    for (int s = 0; s < 5; ++s) {
      k_tapsA<<<dim3(TGRID, 1), 256, 0, stream>>>(calib, TAPS, s);
      k_sampleA<<<dim3(NBOX / 8, 3, 1), 512, 0, stream>>>(II, TAPS, VOXT, s);
      k_gemmT<<<dim3(NBLK0, 2, 4), 256, 0, stream>>>(
          VOXT, WPERMT + (size_t)s * 589824, PART);
      k_redoft<<<NBOX, 256, 0, stream>>>(PART, BETA + s * 256, XBUF, s * 256);
    }
    k_means2<<<(NBOX + 63) / 64, 256, 0, stream>>>(XBUF, MEANS);
  }

  k_att<<<5, 256, 0, stream>>>(MEANS, att_w, att_b, SATT);
  k_wperm1T<<<256, 256, 0, stream>>>(conv1_w, SATT, WC1T);

  k_gemmS<1><<<dim3(NBLKC, 2, 9), 512, 0, stream>>>(XBUF, WC1T, PART, ZPAGE);
  k_redconv<false><<<NPIX, 256, 0, stream>>>(PART, ALPHA + 5 * 256, BETA + 5 * 256, Y1);

  k_gemmS<2><<<dim3(NBLKC, 2, 9), 512, 0, stream>>>(Y1, WC2T, PART, ZPAGE);
  k_redconv<true><<<NPIX, 256, 0, stream>>>(PART, ALPHA + 6 * 256, BETA + 6 * 256, d_out);
}